// Round 12
// baseline (5055.035 us; speedup 1.0000x reference)
//
#include <hip/hip_runtime.h>
#include <hip/hip_bf16.h>

#define B_ 64
#define S_ 2048
#define T_ 256
#define NB 4   // batches per WG
#define CPB 4  // chains per batch (16 chains/WG, grid = 4)

typedef __attribute__((ext_vector_type(8))) short bf16x8;
typedef __attribute__((ext_vector_type(4))) float f32x4;

template <int CTRL>
__device__ __forceinline__ float dpp_max(float v) {
  const int t = __builtin_amdgcn_update_dpp(0, __builtin_bit_cast(int, v), CTRL, 0xF, 0xF, true);
  return fmaxf(v, __builtin_bit_cast(float, t));
}
template <int CTRL>
__device__ __forceinline__ float dpp_add(float v) {
  const int t = __builtin_amdgcn_update_dpp(0, __builtin_bit_cast(int, v), CTRL, 0xF, 0xF, true);
  return v + __builtin_bit_cast(float, t);
}

__device__ __forceinline__ unsigned short f2bf(float f) {  // RNE bf16
  unsigned u = __builtin_bit_cast(unsigned, f);
  u += 0x7FFFu + ((u >> 16) & 1u);
  return (unsigned short)(u >> 16);
}

__device__ __forceinline__ f32x4 mfma16(bf16x8 a, bf16x8 b, f32x4 c) {
  return __builtin_amdgcn_mfma_f32_16x16x32_bf16(a, b, c, 0, 0, 0);
}

// async global->LDS, 4 bytes/lane; LDS dest = wave-uniform base + lane*4
__device__ __forceinline__ void stage4(const float* g, float* l) {
#if __has_builtin(__builtin_amdgcn_global_load_lds)
  __builtin_amdgcn_global_load_lds(
      (const __attribute__((address_space(1))) unsigned*)g,
      (__attribute__((address_space(3))) unsigned*)l, 4, 0, 0);
#else
  *l = *g;
#endif
}

// lgkm-only barrier: LDS visibility without draining in-flight global stages
__device__ __forceinline__ void wg_barrier() {
  __builtin_amdgcn_sched_barrier(0);
  asm volatile("s_waitcnt lgkmcnt(0)" ::: "memory");
  __builtin_amdgcn_s_barrier();
  asm volatile("" ::: "memory");
  __builtin_amdgcn_sched_barrier(0);
}

// ---------------- numerator score: ws[b] ----------------
__global__ void crf_score(const float* __restrict__ em, const int* __restrict__ tags,
                          const int* __restrict__ mask, const float* __restrict__ trans,
                          const float* __restrict__ startt, const float* __restrict__ endt,
                          float* __restrict__ ws) {
  const int b = blockIdx.x;
  const int t = threadIdx.x;  // 256
  const int* tg = tags + b * S_;
  const int* mk = mask + b * S_;
  const float* eb = em + (size_t)b * S_ * T_;

  float sc = 0.f;
  int msum = 0;
  for (int s = t; s < S_; s += 256) {
    const int tag = tg[s];
    const int m = mk[s];
    msum += m;
    const float e = eb[(size_t)s * T_ + tag];
    if (s == 0) {
      sc += startt[tag] + e;
    } else {
      const int pt = tg[s - 1];
      sc += (trans[tag * T_ + pt] + e) * (float)m;
    }
  }
#pragma unroll
  for (int off = 32; off > 0; off >>= 1) {
    sc += __shfl_down(sc, off);
    msum += __shfl_down(msum, off);
  }
  __shared__ float ssc[4];
  __shared__ int smc[4];
  const int wv = t >> 6, ln = t & 63;
  if (ln == 0) { ssc[wv] = sc; smc[wv] = msum; }
  __syncthreads();
  if (t == 0) {
    const float s4 = (ssc[0] + ssc[1]) + (ssc[2] + ssc[3]);
    const int m4 = smc[0] + smc[1] + smc[2] + smc[3];
    const int last = tg[m4 - 1];
    ws[b] = s4 + endt[last];
  }
}

// ---------------- forward (log Z): 4 batches x 4 chains per WG ----------------
// One barrier interval advances ALL 4 batches one step: sync/latency overhead
// amortized 4x. W-frags shared (128 VGPRs). E via global_load_lds into a 2-slot
// LDS ring (each wave stages/reads only its own 64-j segment -> vmcnt wave-local;
// exp precomputed one step ahead off-chain). Renorm: exact 1-stale pow2 per batch
// from post-E stored-x max (r11-proven), integer k_run.
#define STEP(RB, WB)                                                              \
  {                                                                               \
    float rs_[NB];                                                                \
    _Pragma("unroll") for (int b = 0; b < NB; ++b) {                              \
      const float4 q = ((const float4*)&mpT[RB][b][0])[l & 3];                    \
      float mh = fmaxf(fmaxf(q.x, q.y), fmaxf(q.z, q.w));                         \
      mh = dpp_max<0xB1>(mh);                                                     \
      mh = dpp_max<0x4E>(mh);                                                     \
      int ue = (int)(__builtin_bit_cast(unsigned, mh) >> 23) - 127;               \
      ue = (ue < -20) ? -20 : ue;                                                 \
      ue += 8;                                                                    \
      k_run[b] += ue;                                                             \
      rs_[b] = __builtin_bit_cast(float, (unsigned)((127 - ue) << 23));           \
    }                                                                             \
    _Pragma("unroll") for (int b = 0; b < NB; ++b) {                              \
      const unsigned char* xb = &Xl[b][RB][0];                                    \
      f32x4 z4 = {0.f, 0.f, 0.f, 0.f};                                            \
      f32x4 aL0 = z4, aL1 = z4, aL2 = z4, aL3 = z4;                               \
      f32x4 aH0 = z4, aH1 = z4, aH2 = z4, aH3 = z4;                               \
      _Pragma("unroll") for (int kk = 0; kk < 4; ++kk) {                          \
        const bf16x8 av = *(const bf16x8*)(xb + raddr[kk]);                       \
        aL0 = mfma16(av, wf[0][kk], aL0);                                         \
        aL1 = mfma16(av, wf[1][kk], aL1);                                         \
        aL2 = mfma16(av, wf[2][kk], aL2);                                         \
        aL3 = mfma16(av, wf[3][kk], aL3);                                         \
      }                                                                           \
      _Pragma("unroll") for (int kk = 4; kk < 8; ++kk) {                          \
        const bf16x8 av = *(const bf16x8*)(xb + raddr[kk]);                       \
        aH0 = mfma16(av, wf[0][kk], aH0);                                         \
        aH1 = mfma16(av, wf[1][kk], aH1);                                         \
        aH2 = mfma16(av, wf[2][kk], aH2);                                         \
        aH3 = mfma16(av, wf[3][kk], aH3);                                         \
      }                                                                           \
      const f32x4 ac0 = aL0 + aH0, ac1 = aL1 + aH1;                               \
      const f32x4 ac2 = aL2 + aH2, ac3 = aL3 + aH3;                               \
      float xfb[4];                                                               \
      _Pragma("unroll") for (int r = 0; r < 4; ++r) {                             \
        const float s01 = (hi & 1) ? ac1[r] : ac0[r];                             \
        const float s23 = (hi & 1) ? ac3[r] : ac2[r];                             \
        const float val = (hi & 2) ? s23 : s01;                                   \
        xfb[r] = val * Epre[b][r] * rs_[b];                                       \
      }                                                                           \
      float mx = fmaxf(fmaxf(xfb[0], xfb[1]), fmaxf(xfb[2], xfb[3]));             \
      mx = dpp_max<0xB1>(mx);                                                     \
      mx = dpp_max<0x4E>(mx);                                                     \
      mx = dpp_max<0x141>(mx);                                                    \
      mx = dpp_max<0x140>(mx);                                                    \
      if (lo == 0) mpT[WB][b][w * 4 + hi] = mx;                                   \
      _Pragma("unroll") for (int r = 0; r < 4; ++r)                               \
        *(unsigned short*)(&Xl[b][WB][0] + waddr[r]) = f2bf(xfb[r]);              \
    }                                                                             \
    asm volatile("s_waitcnt vmcnt(0)" ::: "memory");                              \
    __builtin_amdgcn_sched_barrier(0);                                            \
    _Pragma("unroll") for (int b = 0; b < NB; ++b)                                \
      _Pragma("unroll") for (int r = 0; r < 4; ++r)                               \
        Epre[b][r] = __expf(Ering[RB][b][r][jE]);                                 \
    _Pragma("unroll") for (int b = 0; b < NB; ++b)                                \
      _Pragma("unroll") for (int r = 0; r < 4; ++r)                               \
        stage4(emL + cOff[b][r] + rowf, &Ering[WB][b][r][jE]);                    \
    rowf = (rowf < 2047u * 256u) ? rowf + 256u : rowf;                            \
    wg_barrier();                                                                 \
  }

__global__ __launch_bounds__(256, 1) void crf_forward(
    const float* __restrict__ em, const float* __restrict__ trans,
    const float* __restrict__ startt, const float* __restrict__ endt,
    float* __restrict__ ws) {
  const int tid = threadIdx.x;
  const int w = tid >> 6;
  const int l = tid & 63;
  const int lo = l & 15;
  const int hi = l >> 4;
  const int c4 = lo & 3;
  const int b0 = blockIdx.x * (NB * CPB);

  __shared__ __align__(16) unsigned char Xl[NB][2][2048];   // x bf16, swizzled
  __shared__ __align__(16) float Ering[2][NB][CPB][T_];     // raw em ring (32 KB)
  __shared__ __align__(16) float mpT[2][NB][16];
  __shared__ float fintab[NB][4][4];
  __shared__ float fsum[NB][4];

  // ---- W fragments (B-operand), shared by all batches: 128 VGPRs
  bf16x8 wf[4][8];
#pragma unroll
  for (int t = 0; t < 4; ++t) {
    const int j = 64 * w + 16 * t + lo;
#pragma unroll
    for (int kk = 0; kk < 8; ++kk) {
      bf16x8 v;
#pragma unroll
      for (int e = 0; e < 8; ++e) {
        const int k = kk * 32 + hi * 8 + e;
        v[e] = (short)f2bf(__expf(trans[k * T_ + j]));
      }
      wf[t][kk] = v;
    }
  }

  // ---- addresses (within one 2KB Xl block; unit-XOR swizzle by chain)
  unsigned raddr[8];
#pragma unroll
  for (int kk = 0; kk < 8; ++kk)
    raddr[kk] = (unsigned)(c4 * 512 + 16 * (((4 * kk + hi) ^ (c4 << 2)) & 31));
  const int jE = 64 * w + 16 * hi + lo;  // == 64*w + l
  unsigned waddr[4];
#pragma unroll
  for (int r = 0; r < 4; ++r)
    waddr[r] = (unsigned)(r * 512 + 16 * (((jE >> 3) ^ (r << 2)) & 31) + (jE & 7) * 2);
  const float* emL = em + jE;  // per-lane base
  unsigned cOff[NB][CPB];      // uniform -> SGPRs
#pragma unroll
  for (int b = 0; b < NB; ++b)
#pragma unroll
    for (int r = 0; r < CPB; ++r)
      cOff[b][r] = (unsigned)((b0 + b * CPB + r) * (S_ * T_));

  // ---- init: al0 = start + em[.,0,.]; exact per-batch max m0[b]
  float m0[NB];
  float Epre[NB][4];
  int k_run[NB];
  const float st = startt[jE];
  {
    float al[NB][4];
#pragma unroll
    for (int b = 0; b < NB; ++b) {
#pragma unroll
      for (int r = 0; r < 4; ++r) al[b][r] = st + emL[cOff[b][r]];
      float lm = fmaxf(fmaxf(al[b][0], al[b][1]), fmaxf(al[b][2], al[b][3]));
      lm = dpp_max<0xB1>(lm);
      lm = dpp_max<0x4E>(lm);
      lm = dpp_max<0x141>(lm);
      lm = dpp_max<0x140>(lm);
      lm = fmaxf(lm, __shfl_xor(lm, 16));
      lm = fmaxf(lm, __shfl_xor(lm, 32));
      if (l == 0) fsum[b][w] = lm;
    }
    __syncthreads();
#pragma unroll
    for (int b = 0; b < NB; ++b) {
      m0[b] = fmaxf(fmaxf(fsum[b][0], fsum[b][1]), fmaxf(fsum[b][2], fsum[b][3]));
#pragma unroll
      for (int r = 0; r < 4; ++r) {
        const float x0 = __expf(al[b][r] - m0[b]);
        *(unsigned short*)(&Xl[b][0][0] + waddr[r]) = f2bf(x0);
      }
      k_run[b] = 0;
#pragma unroll
      for (int r = 0; r < 4; ++r) Epre[b][r] = __expf(emL[cOff[b][r] + 256]);  // row 1
    }
    if (tid < 64) mpT[0][tid >> 4][tid & 15] = 1.0f;  // max(x0) == 1 exactly
    // prologue: stage rows 2 -> slot 0
#pragma unroll
    for (int b = 0; b < NB; ++b)
#pragma unroll
      for (int r = 0; r < 4; ++r)
        stage4(emL + cOff[b][r] + 2 * 256, &Ering[0][b][r][jE]);
  }
  unsigned rowf = 3u * 256u;  // first in-loop stage: rows 3
  __syncthreads();

  // ---- main loop: steps 1..2046 as pairs, tail 2047
  for (int p2 = 0; p2 < (S_ - 2) / 2; ++p2) {
    STEP(0, 1)
    STEP(1, 0)
  }

  // ---- tail step s = 2047 (RB = 0): no store, no barrier
  float xtail[NB][4];
  {
#pragma unroll
    for (int b = 0; b < NB; ++b) {
      const float4 q = ((const float4*)&mpT[0][b][0])[l & 3];
      float mh = fmaxf(fmaxf(q.x, q.y), fmaxf(q.z, q.w));
      mh = dpp_max<0xB1>(mh);
      mh = dpp_max<0x4E>(mh);
      int ue = (int)(__builtin_bit_cast(unsigned, mh) >> 23) - 127;
      ue = (ue < -20) ? -20 : ue;
      ue += 8;
      k_run[b] += ue;
      const float rs = __builtin_bit_cast(float, (unsigned)((127 - ue) << 23));
      const unsigned char* xb = &Xl[b][0][0];
      f32x4 z4 = {0.f, 0.f, 0.f, 0.f};
      f32x4 aL0 = z4, aL1 = z4, aL2 = z4, aL3 = z4;
      f32x4 aH0 = z4, aH1 = z4, aH2 = z4, aH3 = z4;
#pragma unroll
      for (int kk = 0; kk < 4; ++kk) {
        const bf16x8 av = *(const bf16x8*)(xb + raddr[kk]);
        aL0 = mfma16(av, wf[0][kk], aL0);
        aL1 = mfma16(av, wf[1][kk], aL1);
        aL2 = mfma16(av, wf[2][kk], aL2);
        aL3 = mfma16(av, wf[3][kk], aL3);
      }
#pragma unroll
      for (int kk = 4; kk < 8; ++kk) {
        const bf16x8 av = *(const bf16x8*)(xb + raddr[kk]);
        aH0 = mfma16(av, wf[0][kk], aH0);
        aH1 = mfma16(av, wf[1][kk], aH1);
        aH2 = mfma16(av, wf[2][kk], aH2);
        aH3 = mfma16(av, wf[3][kk], aH3);
      }
      const f32x4 ac0 = aL0 + aH0, ac1 = aL1 + aH1;
      const f32x4 ac2 = aL2 + aH2, ac3 = aL3 + aH3;
#pragma unroll
      for (int r = 0; r < 4; ++r) {
        const float s01 = (hi & 1) ? ac1[r] : ac0[r];
        const float s23 = (hi & 1) ? ac3[r] : ac2[r];
        const float val = (hi & 2) ? s23 : s01;
        xtail[b][r] = val * Epre[b][r] * rs;
      }
    }
  }

  // ---- epilogue: logZ[c] = m0[b] + k_run[b]*ln2 + log(sum_j x*exp(end_j))
  const float ee = __expf(endt[jE]);
#pragma unroll
  for (int b = 0; b < NB; ++b) {
    float fr[4];
#pragma unroll
    for (int r = 0; r < 4; ++r) {
      float f = xtail[b][r] * ee;
      f = dpp_add<0xB1>(f);
      f = dpp_add<0x4E>(f);
      f = dpp_add<0x141>(f);
      f = dpp_add<0x140>(f);
      f += __shfl_xor(f, 16);
      f += __shfl_xor(f, 32);
      fr[r] = f;
    }
    if (l == 0) {
      float4 fv;
      fv.x = fr[0]; fv.y = fr[1]; fv.z = fr[2]; fv.w = fr[3];
      *(float4*)&fintab[b][w][0] = fv;
    }
  }
  __syncthreads();
  if (tid < NB * CPB) {
    const int b = tid >> 2, r = tid & 3;
    const float tot = (fintab[b][0][r] + fintab[b][1][r]) +
                      (fintab[b][2][r] + fintab[b][3][r]);
    ws[64 + b0 + tid] = m0[b] + (float)k_run[b] * 0.6931471805599453f + __logf(tot);
  }
}

// ---------------- final: mean_b(score - logZ) ----------------
__global__ void crf_final(const float* __restrict__ ws, float* __restrict__ out) {
  const int t = threadIdx.x;  // 64
  float v = ws[t] - ws[64 + t];
#pragma unroll
  for (int off = 1; off <= 32; off <<= 1) v += __shfl_xor(v, off);
  if (t == 0) out[0] = v * (1.0f / 64.0f);
}

extern "C" void kernel_launch(void* const* d_in, const int* in_sizes, int n_in,
                              void* d_out, int out_size, void* d_ws, size_t ws_size,
                              hipStream_t stream) {
  const float* em = (const float*)d_in[0];
  const int* tags = (const int*)d_in[1];
  const int* mask = (const int*)d_in[2];
  const float* trans = (const float*)d_in[3];
  const float* startt = (const float*)d_in[4];
  const float* endt = (const float*)d_in[5];
  float* out = (float*)d_out;
  float* ws = (float*)d_ws;

  crf_score<<<B_, 256, 0, stream>>>(em, tags, mask, trans, startt, endt, ws);
  crf_forward<<<B_ / (NB * CPB), 256, 0, stream>>>(em, trans, startt, endt, ws);
  crf_final<<<1, 64, 0, stream>>>(ws, out);
}

// Round 13
// 1258.068 us; speedup vs baseline: 4.0181x; 4.0181x over previous
//
#include <hip/hip_runtime.h>
#include <hip/hip_bf16.h>

#define B_ 64
#define S_ 2048
#define T_ 256

typedef _Float16 half2_t __attribute__((ext_vector_type(2)));

__device__ __forceinline__ float fdot2f(half2_t a, half2_t b, float c) {
  return __builtin_amdgcn_fdot2(a, b, c, false);
}
__device__ __forceinline__ half2_t pack2(float a, float b) {
  return __builtin_bit_cast(half2_t, __builtin_amdgcn_cvt_pkrtz(a, b));
}
template <int CTRL>
__device__ __forceinline__ float dpp_max(float v) {
  const int t = __builtin_amdgcn_update_dpp(0, __builtin_bit_cast(int, v), CTRL, 0xF, 0xF, true);
  return fmaxf(v, __builtin_bit_cast(float, t));
}
template <int CTRL>
__device__ __forceinline__ float dpp_add(float v) {
  const int t = __builtin_amdgcn_update_dpp(0, __builtin_bit_cast(int, v), CTRL, 0xF, 0xF, true);
  return v + __builtin_bit_cast(float, t);
}

// lgkm-only barrier: LDS visibility without draining in-flight global prefetch
__device__ __forceinline__ void wg_barrier() {
  __builtin_amdgcn_sched_barrier(0);
  asm volatile("s_waitcnt lgkmcnt(0)" ::: "memory");
  __builtin_amdgcn_s_barrier();
  asm volatile("" ::: "memory");
  __builtin_amdgcn_sched_barrier(0);
}

// ---------------- numerator score: ws[b] ----------------
__global__ void crf_score(const float* __restrict__ em, const int* __restrict__ tags,
                          const int* __restrict__ mask, const float* __restrict__ trans,
                          const float* __restrict__ startt, const float* __restrict__ endt,
                          float* __restrict__ ws) {
  const int b = blockIdx.x;
  const int t = threadIdx.x;  // 256
  const int* tg = tags + b * S_;
  const int* mk = mask + b * S_;
  const float* eb = em + (size_t)b * S_ * T_;

  float sc = 0.f;
  int msum = 0;
  for (int s = t; s < S_; s += 256) {
    const int tag = tg[s];
    const int m = mk[s];
    msum += m;
    const float e = eb[(size_t)s * T_ + tag];
    if (s == 0) {
      sc += startt[tag] + e;
    } else {
      const int pt = tg[s - 1];
      sc += (trans[tag * T_ + pt] + e) * (float)m;
    }
  }
#pragma unroll
  for (int off = 32; off > 0; off >>= 1) {
    sc += __shfl_down(sc, off);
    msum += __shfl_down(msum, off);
  }
  __shared__ float ssc[4];
  __shared__ int smc[4];
  const int wv = t >> 6, ln = t & 63;
  if (ln == 0) { ssc[wv] = sc; smc[wv] = msum; }
  __syncthreads();
  if (t == 0) {
    const float s4 = (ssc[0] + ssc[1]) + (ssc[2] + ssc[3]);
    const int m4 = smc[0] + smc[1] + smc[2] + smc[3];
    const int last = tg[m4 - 1];
    ws[b] = s4 + endt[last];
  }
}

// ---------------- forward algorithm (log Z): ws[64+b] ----------------
// r8 structure (best: 610 ns/step), launched at grid=256 with 4x redundant
// chains (b = blockIdx.x & 63) to put a WG on every CU. Redundant WGs compute
// bit-identical results and store identical values (deterministic). This tests
// (and exploits, if true) the low-clock-at-low-occupancy hypothesis.
__global__ __launch_bounds__(256, 1) void crf_forward(
    const float* __restrict__ em, const float* __restrict__ trans,
    const float* __restrict__ startt, const float* __restrict__ endt,
    float* __restrict__ ws) {
  const int b = blockIdx.x & 63;  // 4x redundancy across 256 WGs
  const int tid = threadIdx.x;    // 0..255
  const int jg = tid >> 3;        // 0..31
  const int ig = tid & 7;         // 0..7
  const int wv = tid >> 6;        // wave 0..3
  const int lane = tid & 63;
  const float* eb = em + (size_t)b * S_ * T_;

  __shared__ __align__(16) unsigned char aPb[2][512];  // alpha f16, rotated 16B units
  __shared__ __align__(16) float ebuf[2][8][T_];       // staged exp(emissions)
  __shared__ float wredq[2][16];                       // per-16-lane maxes, 2-slot ring
  __shared__ float fsum[4];

  // --- one-time: W tile (32 i x 8 j) as 128 half2
  half2_t w2[16][8];
#pragma unroll
  for (int q = 0; q < 16; ++q) {
    const int i0 = 32 * ig + 2 * q;
#pragma unroll
    for (int h = 0; h < 8; ++h) {
      const int j = 8 * jg + h;
      w2[q][h] = pack2(__expf(trans[i0 * T_ + j]), __expf(trans[(i0 + 1) * T_ + j]));
    }
  }

  // a-read offsets: logical 16B unit r of block ig at phys unit 4ig + ((r+ig)&3)
  int roff[4];
#pragma unroll
  for (int r = 0; r < 4; ++r) roff[r] = (4 * ig + ((r + ig) & 3)) * 16;
  const int w_blk = jg >> 2;
  const int wbyte = (4 * w_blk + (((jg & 3) + w_blk) & 3)) * 16;

  // --- init: al0 = start + em[0] (replicated across ig), exact max m0
  const float4 sa = *(const float4*)(startt + 8 * jg);
  const float4 sb = *(const float4*)(startt + 8 * jg + 4);
  const float4 ea = *(const float4*)(eb + 8 * jg);
  const float4 eb4 = *(const float4*)(eb + 8 * jg + 4);
  float al[8] = {sa.x + ea.x, sa.y + ea.y, sa.z + ea.z, sa.w + ea.w,
                 sb.x + eb4.x, sb.y + eb4.y, sb.z + eb4.z, sb.w + eb4.w};
  float lm = al[0];
#pragma unroll
  for (int h = 1; h < 8; ++h) lm = fmaxf(lm, al[h]);
  lm = dpp_max<0xB1>(lm);
  lm = dpp_max<0x4E>(lm);
  lm = dpp_max<0x141>(lm);
  lm = dpp_max<0x140>(lm);
  lm = fmaxf(lm, __shfl_xor(lm, 16));
  lm = fmaxf(lm, __shfl_xor(lm, 32));
  if (lane == 0) fsum[wv] = lm;
  __syncthreads();
  float m0 = fmaxf(fmaxf(fsum[0], fsum[1]), fmaxf(fsum[2], fsum[3]));

  float xf[8];
#pragma unroll
  for (int h = 0; h < 8; ++h) xf[h] = __expf(al[h] - m0);
  if (ig == 0) {
    union { half2_t h[4]; float4 f; } uu;
    uu.h[0] = pack2(xf[0], xf[1]); uu.h[1] = pack2(xf[2], xf[3]);
    uu.h[2] = pack2(xf[4], xf[5]); uu.h[3] = pack2(xf[6], xf[7]);
    *(float4*)(aPb[1] + wbyte) = uu.f;
  }
  if (tid < 16) wredq[0][tid] = 1.0f;  // max(x0) == 1 exactly
  // stage chunk 0 (rows 1..8): wave wv does chunk-rows {2wv, 2wv+1}
  const int col = lane * 4;
  {
    float4 f0 = *(const float4*)(eb + (size_t)(1 + 2 * wv) * T_ + col);
    float4 f1 = *(const float4*)(eb + (size_t)(2 + 2 * wv) * T_ + col);
    f0.x = __expf(f0.x); f0.y = __expf(f0.y); f0.z = __expf(f0.z); f0.w = __expf(f0.w);
    f1.x = __expf(f1.x); f1.y = __expf(f1.y); f1.z = __expf(f1.z); f1.w = __expf(f1.w);
    *(float4*)&ebuf[0][2 * wv][col] = f0;
    *(float4*)&ebuf[0][2 * wv + 1][col] = f1;
  }
  __syncthreads();
  float4 pre0 = *(const float4*)(eb + (size_t)(9 + 2 * wv) * T_ + col);
  float4 pre1 = *(const float4*)(eb + (size_t)(10 + 2 * wv) * T_ + col);

  int cur = 0;
  int k_run = 0;
  for (int s = 1; s < S_; ++s) {
    const int rb = s & 1;
    const int sc = (s - 1) & 7;
    // ---- 1-stale normalizer from max(x_{s-1}) (off critical path)
    const float4 wr = *(const float4*)&wredq[(s + 1) & 1][(tid & 3) * 4];
    float mh = fmaxf(fmaxf(wr.x, wr.y), fmaxf(wr.z, wr.w));
    mh = dpp_max<0xB1>(mh);
    mh = dpp_max<0x4E>(mh);
    int ue = (int)(__builtin_bit_cast(unsigned, mh) >> 23) - 127;
    ue = (ue < -20) ? -20 : ue;
    const float rs_f = __builtin_bit_cast(float, (unsigned)((119 - ue) << 23));  // 2^(-ue-8)

    // ---- dot: acc[h] = sum_{i in block ig} a[i] * W[i][8jg+h]  (f32 accum)
    const unsigned char* ab = aPb[rb];
    const float4 blk0 = *(const float4*)(ab + roff[0]);
    const float4 blk1 = *(const float4*)(ab + roff[1]);
    const float4 blk2 = *(const float4*)(ab + roff[2]);
    const float4 blk3 = *(const float4*)(ab + roff[3]);
    float acc[8] = {0.f, 0.f, 0.f, 0.f, 0.f, 0.f, 0.f, 0.f};
    const float4 blks[4] = {blk0, blk1, blk2, blk3};
#pragma unroll
    for (int r = 0; r < 4; ++r) {
      const half2_t a0 = __builtin_bit_cast(half2_t, blks[r].x);
      const half2_t a1 = __builtin_bit_cast(half2_t, blks[r].y);
      const half2_t a2 = __builtin_bit_cast(half2_t, blks[r].z);
      const half2_t a3 = __builtin_bit_cast(half2_t, blks[r].w);
#pragma unroll
      for (int h = 0; h < 8; ++h) {
        acc[h] = fdot2f(a0, w2[4 * r + 0][h], acc[h]);
        acc[h] = fdot2f(a1, w2[4 * r + 1][h], acc[h]);
        acc[h] = fdot2f(a2, w2[4 * r + 2][h], acc[h]);
        acc[h] = fdot2f(a3, w2[4 * r + 3][h], acc[h]);
      }
    }
    // ---- butterfly over 8 i-blocks (lane bits 0..2), f32
#pragma unroll
    for (int h = 0; h < 8; ++h) {
      acc[h] = dpp_add<0xB1>(acc[h]);
      acc[h] = dpp_add<0x4E>(acc[h]);
      acc[h] = dpp_add<0x141>(acc[h]);
    }
    // ---- x = acc * rs * E in ALL lanes (post-E max keeps renorm stable)
    const float4 E0 = *(const float4*)&ebuf[cur][sc][8 * jg];
    const float4 E1 = *(const float4*)&ebuf[cur][sc][8 * jg + 4];
    xf[0] = acc[0] * rs_f * E0.x; xf[1] = acc[1] * rs_f * E0.y;
    xf[2] = acc[2] * rs_f * E0.z; xf[3] = acc[3] * rs_f * E0.w;
    xf[4] = acc[4] * rs_f * E1.x; xf[5] = acc[5] * rs_f * E1.y;
    xf[6] = acc[6] * rs_f * E1.z; xf[7] = acc[7] * rs_f * E1.w;
    // ---- this step's max of stored x -> 16-lane partials (consumed next step)
    float mx = fmaxf(fmaxf(fmaxf(xf[0], xf[1]), fmaxf(xf[2], xf[3])),
                     fmaxf(fmaxf(xf[4], xf[5]), fmaxf(xf[6], xf[7])));
    mx = dpp_max<0x140>(mx);  // bit3 (bits 0..2 uniform post-butterfly)
    if ((lane & 15) == 0) wredq[s & 1][wv * 4 + (lane >> 4)] = mx;
    // ---- writers: pack to f16, single b128 store
    if (ig == 0) {
      union { half2_t h[4]; float4 f; } uu;
      uu.h[0] = pack2(xf[0], xf[1]); uu.h[1] = pack2(xf[2], xf[3]);
      uu.h[2] = pack2(xf[4], xf[5]); uu.h[3] = pack2(xf[6], xf[7]);
      *(float4*)(aPb[rb ^ 1] + wbyte) = uu.f;
    }
    k_run += ue + 8;  // exact integer bookkeeping of applied 2^-(ue+8) scales
    // ---- chunk staging every 8 steps
    if (sc == 7) {
      const int nxt = cur ^ 1;
      float4 f0 = pre0, f1 = pre1;
      f0.x = __expf(f0.x); f0.y = __expf(f0.y); f0.z = __expf(f0.z); f0.w = __expf(f0.w);
      f1.x = __expf(f1.x); f1.y = __expf(f1.y); f1.z = __expf(f1.z); f1.w = __expf(f1.w);
      *(float4*)&ebuf[nxt][2 * wv][col] = f0;
      *(float4*)&ebuf[nxt][2 * wv + 1][col] = f1;
      const int ck2 = ((s - 1) >> 3) + 2;
      if (ck2 < S_ / 8) {
        int row0 = 1 + ck2 * 8 + 2 * wv;
        int row1 = row0 + 1;
        if (row0 > S_ - 1) row0 = S_ - 1;
        if (row1 > S_ - 1) row1 = S_ - 1;
        pre0 = *(const float4*)(eb + (size_t)row0 * T_ + col);
        pre1 = *(const float4*)(eb + (size_t)row1 * T_ + col);
      }
      cur = nxt;
    }
    wg_barrier();
  }

  // ---- epilogue: log_z = m0 + k_run*ln2 + log(sum_j x[j] * exp(end[j]))
  float fin = 0.f;
  if (ig == 0) {
    const float4 en0 = *(const float4*)(endt + 8 * jg);
    const float4 en1 = *(const float4*)(endt + 8 * jg + 4);
    fin = xf[0] * __expf(en0.x) + xf[1] * __expf(en0.y) +
          xf[2] * __expf(en0.z) + xf[3] * __expf(en0.w) +
          xf[4] * __expf(en1.x) + xf[5] * __expf(en1.y) +
          xf[6] * __expf(en1.z) + xf[7] * __expf(en1.w);
  }
  fin = dpp_add<0xB1>(fin);
  fin = dpp_add<0x4E>(fin);
  fin = dpp_add<0x141>(fin);
  fin = dpp_add<0x140>(fin);
  fin += __shfl_xor(fin, 16);
  fin += __shfl_xor(fin, 32);
  __syncthreads();  // reuse fsum safely
  if (lane == 0) fsum[wv] = fin;
  __syncthreads();
  if (tid == 0) {
    const float tot = (fsum[0] + fsum[1]) + (fsum[2] + fsum[3]);
    ws[64 + b] = m0 + (float)k_run * 0.6931471805599453f + __logf(tot);
  }
}

// ---------------- final: mean_b(score - logZ) ----------------
__global__ void crf_final(const float* __restrict__ ws, float* __restrict__ out) {
  const int t = threadIdx.x;  // 64
  float v = ws[t] - ws[64 + t];
#pragma unroll
  for (int off = 1; off <= 32; off <<= 1) v += __shfl_xor(v, off);
  if (t == 0) out[0] = v * (1.0f / 64.0f);
}

extern "C" void kernel_launch(void* const* d_in, const int* in_sizes, int n_in,
                              void* d_out, int out_size, void* d_ws, size_t ws_size,
                              hipStream_t stream) {
  const float* em = (const float*)d_in[0];
  const int* tags = (const int*)d_in[1];
  const int* mask = (const int*)d_in[2];
  const float* trans = (const float*)d_in[3];
  const float* startt = (const float*)d_in[4];
  const float* endt = (const float*)d_in[5];
  float* out = (float*)d_out;
  float* ws = (float*)d_ws;

  crf_score<<<B_, 256, 0, stream>>>(em, tags, mask, trans, startt, endt, ws);
  crf_forward<<<256, 256, 0, stream>>>(em, trans, startt, endt, ws);  // 4x redundant
  crf_final<<<1, 64, 0, stream>>>(ws, out);
}